// Round 13
// baseline (227.113 us; speedup 1.0000x reference)
//
#include <hip/hip_runtime.h>

using f16   = _Float16;
using f16x4 = __attribute__((ext_vector_type(4))) _Float16;
using f16x8 = __attribute__((ext_vector_type(8))) _Float16;
using f32x4 = __attribute__((ext_vector_type(4))) float;
using u32x4 = __attribute__((ext_vector_type(4))) unsigned int;
using fp16x2_raw = __fp16 __attribute__((ext_vector_type(2)));

#define MFMA16(a, b, c) __builtin_amdgcn_mfma_f32_16x16x32_f16((a), (b), (c), 0, 0, 0)

namespace {
constexpr int kT = 8, kWd = 14, kS = 196;
constexpr int kN = 1568;      // T*S (sequence length per batch)
constexpr int kM = 3136;      // B*N (GEMM rows)
constexpr int kHeads = 12;
constexpr int kNp = 1664;     // padded N (13*128)
constexpr float kLog2e = 1.4426950408889634f;
// workspace byte offsets (all 256-aligned); total 25378816 (proven budget)
constexpr size_t OFF_WH   = 0;            // Wh   [2304][768] f16
constexpr size_t OFF_WP   = 3538944;      // Wp   [768][768]  f16
constexpr size_t OFF_Q    = 4718592;      // qf   [24][Np][64] f16 (q*log2e); REUSED as O
constexpr size_t OFF_XH   = 9830400;      // Xh   [3136][768] f16 (x converted)
constexpr size_t OFF_KF   = 14942208;     // kfrag[24][13][8][2][64][8] f16
constexpr size_t OFF_KONE = 20054016;     // konefrag [13][8][2][64][8] f16
constexpr size_t OFF_VSWZ = 20267008;     // vswz [24][13][4][4][64][8] f16
constexpr size_t WS_TOTAL = 25378816;
constexpr int kKoneTot = 13 * 8 * 2 * 64 * 8;   // 106496 f16 elements

__device__ inline f16x4 pack4(float4 v) {
  union { fp16x2_raw h2[2]; f16x4 f4; } u;
  u.h2[0] = __builtin_amdgcn_cvt_pkrtz(v.x, v.y);
  u.h2[1] = __builtin_amdgcn_cvt_pkrtz(v.z, v.w);
  return u.f4;
}

__device__ inline float fast_exp2(float x) {
#if __has_builtin(__builtin_amdgcn_exp2f)
  return __builtin_amdgcn_exp2f(x);
#else
  return __expf(x * 0.6931471805599453f);
#endif
}

__device__ inline float dotqR(const f16x8* qh, const float4* R4) {
  float s = 0.f;
#pragma unroll
  for (int i = 0; i < 8; ++i) {
    f16x8 h = qh[i];
    float4 a = R4[2 * i], b = R4[2 * i + 1];
    s += (float)h[0] * a.x + (float)h[1] * a.y + (float)h[2] * a.z + (float)h[3] * a.w
       + (float)h[4] * b.x + (float)h[5] * b.y + (float)h[6] * b.z + (float)h[7] * b.w;
  }
  return s;
}
}

// ---------------- fused fp32->f16 conversion (W, X) + one-hot ext fragments -----
__global__ __launch_bounds__(256) void arp_cvt(
    const float* __restrict__ qkvw, const float* __restrict__ projw,
    const float* __restrict__ X,
    f16* __restrict__ Wh, f16* __restrict__ Wp, f16* __restrict__ Xh,
    f16* __restrict__ konefrag) {
  int gid = blockIdx.x * 256 + threadIdx.x;
  const int NQ = (2304 * 768) / 4;
  const int NP = (768 * 768) / 4;
  const int NX = (3136 * 768) / 4;
  if (gid < NQ) {
    *(f16x4*)(Wh + (size_t)gid * 4) = pack4(*(const float4*)(qkvw + (size_t)gid * 4));
  } else if (gid < NQ + NP) {
    int g = gid - NQ;
    *(f16x4*)(Wp + (size_t)g * 4) = pack4(*(const float4*)(projw + (size_t)g * 4));
  } else if (gid < NQ + NP + NX) {
    int g = gid - NQ - NP;
    *(f16x4*)(Xh + (size_t)g * 4) = pack4(*(const float4*)(X + (size_t)g * 4));
  } else {
    int g = gid - NQ - NP - NX;
    if (g < kKoneTot) {
      int j = g & 7;
      int lane = (g >> 3) & 63;
      int s2 = (g >> 9) & 1;
      int nt = (g >> 10) & 7;
      int kt = g >> 13;
      int fr = lane & 15, qd = lane >> 4;
      int key = kt * 128 + nt * 16 + fr;
      int c = s2 * 32 + qd * 8 + j;
      int t2 = key / kS; int rm = key - t2 * kS;
      int h2 = rm / kWd; int w2 = rm - h2 * kWd;
      if (t2 > kT - 1) t2 = kT - 1;
      float v = 0.f;
      if (c == h2) v = 1.f;
      else if (c == 14 + w2) v = 1.f;
      else if (c == 28 + t2) v = 1.f;
      else if (c == 36 && key >= kN) v = 1.f;
      konefrag[g] = (f16)v;
    }
  }
}

// ---------------- QKV GEMM: 128x128, all-f16 operands, register prefetch --------
__global__ __launch_bounds__(256, 2) void arp_gemm_qkv(
    const f16* __restrict__ Xh, const f16* __restrict__ Wh,
    f16* __restrict__ qf, f16* __restrict__ kfrag, f16* __restrict__ vswz) {
  __shared__ char smem[34816];
  f16* sA = (f16*)smem;               // [128][40]
  f16* sB = (f16*)(smem + 10240);     // [128][40]
  f16* sE = (f16*)smem;               // [128][136] (epilogue)
  const int tid = threadIdx.x, lane = tid & 63, wv = tid >> 6;
  const int m0 = blockIdx.y * 128, n0 = blockIdx.x * 128;
  const int wm = (wv & 1) * 64, wn = (wv >> 1) * 64;
  const int frow = lane & 15, quad = lane >> 4, fcol = quad * 8;
  const f32x4 vzero = {0.f, 0.f, 0.f, 0.f};
  f32x4 acc[4][4];
#pragma unroll
  for (int i = 0; i < 4; ++i)
#pragma unroll
    for (int j = 0; j < 4; ++j) acc[i][j] = vzero;

  u32x4 pA[2], pB[2];
  const u32x4 uz = {0, 0, 0, 0};
#pragma unroll
  for (int i = 0; i < 2; ++i) {
    int idx = i * 256 + tid;
    int r = idx >> 2, c8 = (idx & 3) * 8;
    int gm = m0 + r;
    pA[i] = (gm < kM) ? *(const u32x4*)(Xh + (size_t)gm * 768 + c8) : uz;
    pB[i] = *(const u32x4*)(Wh + (size_t)(n0 + r) * 768 + c8);
  }

  for (int kt = 0; kt < 24; ++kt) {
#pragma unroll
    for (int i = 0; i < 2; ++i) {
      int idx = i * 256 + tid;
      int r = idx >> 2, c8 = (idx & 3) * 8;
      *(u32x4*)&sA[r * 40 + c8] = pA[i];
      *(u32x4*)&sB[r * 40 + c8] = pB[i];
    }
    __syncthreads();
    if (kt < 23) {
      int ko = (kt + 1) * 32;
#pragma unroll
      for (int i = 0; i < 2; ++i) {
        int idx = i * 256 + tid;
        int r = idx >> 2, c8 = (idx & 3) * 8;
        int gm = m0 + r;
        pA[i] = (gm < kM) ? *(const u32x4*)(Xh + (size_t)gm * 768 + ko + c8) : uz;
        pB[i] = *(const u32x4*)(Wh + (size_t)(n0 + r) * 768 + ko + c8);
      }
    }
    f16x8 af[4], bf[4];
#pragma unroll
    for (int t = 0; t < 4; ++t) {
      af[t] = *(const f16x8*)&sA[(wm + t * 16 + frow) * 40 + fcol];
      bf[t] = *(const f16x8*)&sB[(wn + t * 16 + frow) * 40 + fcol];
    }
#pragma unroll
    for (int mt = 0; mt < 4; ++mt)
#pragma unroll
      for (int nt = 0; nt < 4; ++nt)
        acc[mt][nt] = MFMA16(af[mt], bf[nt], acc[mt][nt]);
    __syncthreads();
  }

  const int which = n0 / 768;   // 0=q, 1=k, 2=v
  if (which == 2) {
#pragma unroll
    for (int mt = 0; mt < 4; ++mt)
#pragma unroll
      for (int nt = 0; nt < 4; ++nt) {
        int cl = wn + nt * 16 + frow;
#pragma unroll
        for (int rg = 0; rg < 4; ++rg) {
          int rl = wm + mt * 16 + quad * 4 + rg;
          sE[cl * 136 + rl] = (f16)acc[mt][nt][rg];
        }
      }
    __syncthreads();
    int cl = tid >> 1;
    int rb = (tid & 1) * 64;
    int rem = n0 + cl - 1536;
    int hh = rem >> 6, d = rem & 63;
    int td = d >> 4, fr = d & 15;
#pragma unroll
    for (int j = 0; j < 8; ++j) {
      int ms = m0 + rb + j * 8;
      if (ms < kM) {
        int bb = (ms >= kN) ? 1 : 0;
        int ns = ms - bb * kN;
        int bh = bb * kHeads + hh;
        int kt2 = ns >> 7, kr = ns & 127;
        int kc = kr >> 5, qd = (kr >> 3) & 3;
        f16* dst = vswz + ((((size_t)(bh * 13 + kt2)) * 4 + td) * 4 + kc) * 512
                        + (qd * 16 + fr) * 8;
        *(u32x4*)dst = *(const u32x4*)&sE[cl * 136 + rb + j * 8];
      }
    }
  } else {
#pragma unroll
    for (int mt = 0; mt < 4; ++mt) {
      int rbase = m0 + wm + mt * 16 + quad * 4;
#pragma unroll
      for (int nt = 0; nt < 4; ++nt) {
        int col0 = n0 + wn + nt * 16;
        int rem = col0 - which * 768;
        int hh = rem >> 6;
        int d = (rem & 63) + frow;
        int s = d >> 5, qd2 = (d >> 3) & 3, j = d & 7;
#pragma unroll
        for (int rg = 0; rg < 4; ++rg) {
          int m = rbase + rg;
          if (m < kM) {
            int bb = (m >= kN) ? 1 : 0;
            int ns = m - bb * kN;
            int bh = bb * kHeads + hh;
            float av = acc[mt][nt][rg];
            if (which == 0) {
              av *= kLog2e;
              qf[((size_t)bh * kNp + ns) * 64 + d] = (f16)av;
            } else {
              av *= 0.125f;
              int kt2 = ns >> 7, nt2 = (ns >> 4) & 7, fr = ns & 15;
              kfrag[(((size_t)(bh * 13 + kt2) * 8 + nt2) * 2 + s) * 512
                    + (qd2 * 16 + fr) * 8 + j] = (f16)av;
            }
          }
        }
      }
    }
  }
}

// ---------------- flash attention with wave-specialized fused Q-extension -------
// Prologue: wave 0 -> 14 h-dots, wave 1 -> 14 w-dots, wave 2 -> 8 t-dots,
// wave 3 -> mask + zero fill. Branches wave-uniform; row = lane. sQE aliases sKa.
__global__ __launch_bounds__(256, 3) void arp_attn(
    const f16* qf,
    const float* __restrict__ Rh, const float* __restrict__ Rw, const float* __restrict__ Rt,
    const f16* __restrict__ kfrag, const f16* __restrict__ konefrag,
    const f16* __restrict__ vswz, f16* qfO) {
  __shared__ char pool[49152];
  f16* sKa = (f16*)pool;             // 16384 B: K dims 0..63  [nt][s01][64][8]
  f16* sKb = (f16*)(pool + 16384);   // 16384 B: ext dims 64..127
  f16* sV  = (f16*)(pool + 32768);   // 16384 B: V frags [td][kc][64][8]
  f16* sQE = (f16*)pool;             // 8192 B: [64][64] qe staging (prologue only)

  const int tid = threadIdx.x, lane = tid & 63, wv = tid >> 6;
  const int q0 = blockIdx.x * 64;
  const int bh = blockIdx.y;
  const int frow = lane & 15, quad = lane >> 4;
  const f32x4 vzero = {0.f, 0.f, 0.f, 0.f};

  // ---- fused qext, wave-specialized (row = lane, branch uniform per wave) ----
  {
    int q = q0 + lane;
    int qc = (q < kN) ? q : kN - 1;    // clamp so table indices stay in range
    int tq = qc / kS, sr = qc - tq * kS;
    int hq = sr / kWd, wq = sr - hq * kWd;
    if (wv < 3) {
      f16x8 qh[8];
      const f16x8* qv8 = (const f16x8*)(qf + ((size_t)bh * kNp + q) * 64);
#pragma unroll
      for (int i = 0; i < 8; ++i) qh[i] = qv8[i];
      if (wv == 0) {
#pragma unroll
        for (int e = 0; e < 14; ++e)
          sQE[lane * 64 + e] = (f16)dotqR(qh, (const float4*)(Rh + (hq - e + 13) * 64));
      } else if (wv == 1) {
#pragma unroll
        for (int e = 0; e < 14; ++e)
          sQE[lane * 64 + 14 + e] = (f16)dotqR(qh, (const float4*)(Rw + (wq - e + 13) * 64));
      } else {
#pragma unroll
        for (int e = 0; e < 8; ++e)
          sQE[lane * 64 + 28 + e] = (f16)dotqR(qh, (const float4*)(Rt + (tq - e + 7) * 64));
      }
    } else {
      sQE[lane * 64 + 36] = (f16)(-30000.f);
#pragma unroll
      for (int e = 37; e < 64; ++e) sQE[lane * 64 + e] = (f16)0.f;
    }
  }
  __syncthreads();

  f16x8 aQ0, aQ1, aQE0, aQE1;
  {
    int row = q0 + wv * 16 + frow;
    const f16* qp = qf + ((size_t)bh * kNp + row) * 64;
    aQ0 = *(const f16x8*)(qp + quad * 8);
    aQ1 = *(const f16x8*)(qp + 32 + quad * 8);
    int rl = wv * 16 + frow;
    aQE0 = *(const f16x8*)&sQE[rl * 64 + quad * 8];
    aQE1 = *(const f16x8*)&sQE[rl * 64 + 32 + quad * 8];
  }
  f16x8 bOnes;
#pragma unroll
  for (int i = 0; i < 8; ++i) bOnes[i] = (frow == 0) ? (f16)1.f : (f16)0.f;

  f32x4 Oc[5];
#pragma unroll
  for (int t = 0; t < 5; ++t) Oc[t] = vzero;

  const f16* kba = kfrag + (size_t)bh * 13 * 8192;
  const f16* vba = vswz + (size_t)bh * 13 * 8192;
  f16* sPw = (f16*)(pool + wv * 4352);   // per-wave P: [16][136] f16, aliases sKa/sKb

  for (int kt = 0; kt < 13; ++kt) {
    __syncthreads();  // A: prior iter's sP/sV reads (and prologue aQE reads) done
    {
      const f16* kfa = kba + (size_t)kt * 8192;
      const f16* koa = konefrag + (size_t)kt * 8192;
      const f16* vfa = vba + (size_t)kt * 8192;
#pragma unroll
      for (int i = 0; i < 4; ++i) {
        int u = (i * 256 + tid) * 8;
        *(u32x4*)&sKa[u] = *(const u32x4*)(kfa + u);
      }
#pragma unroll
      for (int i = 0; i < 4; ++i) {
        int u = (i * 256 + tid) * 8;
        *(u32x4*)&sKb[u] = *(const u32x4*)(koa + u);
      }
#pragma unroll
      for (int i = 0; i < 4; ++i) {
        int u = (i * 256 + tid) * 8;
        *(u32x4*)&sV[u] = *(const u32x4*)(vfa + u);
      }
    }
    __syncthreads();  // B: staging visible

    f32x4 Sc[8];
#pragma unroll
    for (int nt = 0; nt < 8; ++nt) {
      const f16* ka = &sKa[nt * 1024 + lane * 8];
      const f16* kb = &sKb[nt * 1024 + lane * 8];
      f32x4 s = MFMA16(aQ0, *(const f16x8*)(ka), vzero);
      s = MFMA16(aQ1, *(const f16x8*)(ka + 512), s);
      s = MFMA16(aQE0, *(const f16x8*)(kb), s);
      Sc[nt] = MFMA16(aQE1, *(const f16x8*)(kb + 512), s);
    }
#pragma unroll
    for (int nt = 0; nt < 8; ++nt)
#pragma unroll
      for (int r = 0; r < 4; ++r)
        Sc[nt][r] = fast_exp2(Sc[nt][r]);
    f16x8 bV[4][4];
#pragma unroll
    for (int td = 0; td < 4; ++td)
#pragma unroll
      for (int kc = 0; kc < 4; ++kc)
        bV[td][kc] = *(const f16x8*)&sV[(td * 4 + kc) * 512 + lane * 8];
    __syncthreads();  // C: all QK-phase sKa/sKb reads done; safe to clobber with P

#pragma unroll
    for (int nt = 0; nt < 8; ++nt)
#pragma unroll
      for (int r = 0; r < 4; ++r)
        sPw[(quad * 4 + r) * 136 + nt * 16 + frow] = (f16)Sc[nt][r];
#pragma unroll
    for (int kc = 0; kc < 4; ++kc) {
      f16x8 aP = *(const f16x8*)&sPw[frow * 136 + kc * 32 + quad * 8];
#pragma unroll
      for (int td = 0; td < 4; ++td)
        Oc[td] = MFMA16(aP, bV[td][kc], Oc[td]);
      Oc[4] = MFMA16(aP, bOnes, Oc[4]);
    }
  }
  float lr[4];
#pragma unroll
  for (int r = 0; r < 4; ++r)
    lr[r] = 1.f / __shfl(Oc[4][r], lane & 48, 64);
#pragma unroll
  for (int td = 0; td < 4; ++td)
#pragma unroll
    for (int r = 0; r < 4; ++r) {
      int row = q0 + wv * 16 + quad * 4 + r;
      if (row < kN) {
        float val = Oc[td][r] * lr[r];
        qfO[((size_t)bh * kNp + row) * 64 + td * 16 + frow] = (f16)val;
      }
    }
}

// ---------------- proj GEMM: 64x128 tiles (grid 294 -> full occupancy) ----------
__global__ __launch_bounds__(256, 4) void arp_gemm_proj(
    const f16* A, const f16* __restrict__ Wp,
    const float* __restrict__ bias, float* __restrict__ out) {
  __shared__ f16 sA[64 * 40];     // 5120 B
  __shared__ f16 sB[128 * 40];    // 10240 B
  const int tid = threadIdx.x, lane = tid & 63, wv = tid >> 6;
  const int m0 = blockIdx.y * 64, n0 = blockIdx.x * 128;
  const int frow = lane & 15, quad = lane >> 4, fcol = quad * 8;
  const f32x4 vzero = {0.f, 0.f, 0.f, 0.f};
  f32x4 acc[8];
#pragma unroll
  for (int j = 0; j < 8; ++j) acc[j] = vzero;

  u32x4 pA, pB[2];
  {
    int r = tid >> 2, c8 = (tid & 3) * 8;
    int m = m0 + r;
    int bb = (m >= kN) ? 1 : 0;
    int ns = m - bb * kN;
    pA = *(const u32x4*)(A + ((size_t)(bb * kHeads) * kNp + ns) * 64 + c8);
#pragma unroll
    for (int i = 0; i < 2; ++i) {
      int idx = i * 256 + tid;
      int rb2 = idx >> 2, cb8 = (idx & 3) * 8;
      pB[i] = *(const u32x4*)(Wp + (size_t)(n0 + rb2) * 768 + cb8);
    }
  }

  for (int kt = 0; kt < 24; ++kt) {
    {
      int r = tid >> 2, c8 = (tid & 3) * 8;
      *(u32x4*)&sA[r * 40 + c8] = pA;
#pragma unroll
      for (int i = 0; i < 2; ++i) {
        int idx = i * 256 + tid;
        int rb2 = idx >> 2, cb8 = (idx & 3) * 8;
        *(u32x4*)&sB[rb2 * 40 + cb8] = pB[i];
      }
    }
    __syncthreads();
    if (kt < 23) {
      int k1 = kt + 1;
      int hd = k1 >> 1, dof = (k1 & 1) * 32;
      int r = tid >> 2, c8 = (tid & 3) * 8;
      int m = m0 + r;
      int bb = (m >= kN) ? 1 : 0;
      int ns = m - bb * kN;
      pA = *(const u32x4*)(A + ((size_t)(bb * kHeads + hd) * kNp + ns) * 64 + dof + c8);
#pragma unroll
      for (int i = 0; i < 2; ++i) {
        int idx = i * 256 + tid;
        int rb2 = idx >> 2, cb8 = (idx & 3) * 8;
        pB[i] = *(const u32x4*)(Wp + (size_t)(n0 + rb2) * 768 + k1 * 32 + cb8);
      }
    }
    f16x8 af = *(const f16x8*)&sA[(wv * 16 + frow) * 40 + fcol];
    f16x8 bf[8];
#pragma unroll
    for (int u = 0; u < 8; ++u)
      bf[u] = *(const f16x8*)&sB[(u * 16 + frow) * 40 + fcol];
#pragma unroll
    for (int u = 0; u < 8; ++u)
      acc[u] = MFMA16(af, bf[u], acc[u]);
    __syncthreads();
  }
#pragma unroll
  for (int u = 0; u < 8; ++u) {
    int col = n0 + u * 16 + frow;
    float bv = bias[col];
#pragma unroll
    for (int rg = 0; rg < 4; ++rg) {
      int m = m0 + wv * 16 + quad * 4 + rg;
      out[(size_t)m * 768 + col] = acc[u][rg] + bv;
    }
  }
}

extern "C" void kernel_launch(void* const* d_in, const int* in_sizes, int n_in,
                              void* d_out, int out_size, void* d_ws, size_t ws_size,
                              hipStream_t stream) {
  if (ws_size < WS_TOTAL) return;
  const float* x      = (const float*)d_in[0];
  const float* qkv_w  = (const float*)d_in[1];
  const float* proj_w = (const float*)d_in[2];
  const float* proj_b = (const float*)d_in[3];
  const float* rph    = (const float*)d_in[4];
  const float* rpw    = (const float*)d_in[5];
  const float* rpt    = (const float*)d_in[6];
  char* ws = (char*)d_ws;
  f16* Wh       = (f16*)(ws + OFF_WH);
  f16* Wp       = (f16*)(ws + OFF_WP);
  f16* qf       = (f16*)(ws + OFF_Q);     // becomes O after attn (in-place)
  f16* Xh       = (f16*)(ws + OFF_XH);
  f16* kfrag    = (f16*)(ws + OFF_KF);
  f16* konefrag = (f16*)(ws + OFF_KONE);
  f16* vswz     = (f16*)(ws + OFF_VSWZ);

  const int cvtTot = (2304 * 768 + 768 * 768 + 3136 * 768) / 4 + kKoneTot;
  arp_cvt<<<(cvtTot + 255) / 256, 256, 0, stream>>>(qkv_w, proj_w, x, Wh, Wp, Xh, konefrag);
  arp_gemm_qkv<<<dim3(18, 25), 256, 0, stream>>>(Xh, Wh, qf, kfrag, vswz);
  arp_attn<<<dim3(25, 24), 256, 0, stream>>>(qf, rph, rpw, rpt, kfrag, konefrag, vswz, qf);
  arp_gemm_proj<<<dim3(6, 49), 256, 0, stream>>>(qf, Wp, proj_b, (float*)d_out);
}

// Round 14
// 188.208 us; speedup vs baseline: 1.2067x; 1.2067x over previous
//
#include <hip/hip_runtime.h>

using f16   = _Float16;
using f16x4 = __attribute__((ext_vector_type(4))) _Float16;
using f16x8 = __attribute__((ext_vector_type(8))) _Float16;
using f32x4 = __attribute__((ext_vector_type(4))) float;
using u32x4 = __attribute__((ext_vector_type(4))) unsigned int;
using fp16x2_raw = __fp16 __attribute__((ext_vector_type(2)));

#define MFMA16(a, b, c) __builtin_amdgcn_mfma_f32_16x16x32_f16((a), (b), (c), 0, 0, 0)

namespace {
constexpr int kT = 8, kWd = 14, kS = 196;
constexpr int kN = 1568;      // T*S (sequence length per batch)
constexpr int kM = 3136;      // B*N (GEMM rows)
constexpr int kHeads = 12;
constexpr int kNp = 1664;     // padded N (13*128)
constexpr float kLog2e = 1.4426950408889634f;
// workspace byte offsets (all 256-aligned); total 25378816 (proven budget)
constexpr size_t OFF_WH   = 0;            // Wh   [2304][768] f16
constexpr size_t OFF_WP   = 3538944;      // Wp   [768][768]  f16
constexpr size_t OFF_Q    = 4718592;      // qf   [24][Np][64] f16 (q*log2e); REUSED as O
constexpr size_t OFF_XH   = 9830400;      // Xh   [3136][768] f16 (x converted)
constexpr size_t OFF_KF   = 14942208;     // kfrag[24][13][8][2][64][8] f16
constexpr size_t OFF_KONE = 20054016;     // konefrag [13][8][2][64][8] f16
constexpr size_t OFF_VSWZ = 20267008;     // vswz [24][13][4][4][64][8] f16
constexpr size_t WS_TOTAL = 25378816;
constexpr int kKoneTot = 13 * 8 * 2 * 64 * 8;   // 106496 f16 elements

__device__ inline f16x4 pack4(float4 v) {
  union { fp16x2_raw h2[2]; f16x4 f4; } u;
  u.h2[0] = __builtin_amdgcn_cvt_pkrtz(v.x, v.y);
  u.h2[1] = __builtin_amdgcn_cvt_pkrtz(v.z, v.w);
  return u.f4;
}

__device__ inline float fast_exp2(float x) {
#if __has_builtin(__builtin_amdgcn_exp2f)
  return __builtin_amdgcn_exp2f(x);
#else
  return __expf(x * 0.6931471805599453f);
#endif
}

// dot of 64-dim q (registers, f16) with 64-dim R row (LDS, f16)
__device__ inline float dotqLDS(const f16x8* qh, const f16* Rrow) {
  float s = 0.f;
#pragma unroll
  for (int i = 0; i < 8; ++i) {
    f16x8 a = qh[i];
    f16x8 b = *(const f16x8*)(Rrow + i * 8);
#pragma unroll
    for (int k = 0; k < 8; ++k) s += (float)a[k] * (float)b[k];
  }
  return s;
}
}

// ---------------- fused fp32->f16 conversion (W, X) + one-hot ext fragments -----
__global__ __launch_bounds__(256) void arp_cvt(
    const float* __restrict__ qkvw, const float* __restrict__ projw,
    const float* __restrict__ X,
    f16* __restrict__ Wh, f16* __restrict__ Wp, f16* __restrict__ Xh,
    f16* __restrict__ konefrag) {
  int gid = blockIdx.x * 256 + threadIdx.x;
  const int NQ = (2304 * 768) / 4;
  const int NP = (768 * 768) / 4;
  const int NX = (3136 * 768) / 4;
  if (gid < NQ) {
    *(f16x4*)(Wh + (size_t)gid * 4) = pack4(*(const float4*)(qkvw + (size_t)gid * 4));
  } else if (gid < NQ + NP) {
    int g = gid - NQ;
    *(f16x4*)(Wp + (size_t)g * 4) = pack4(*(const float4*)(projw + (size_t)g * 4));
  } else if (gid < NQ + NP + NX) {
    int g = gid - NQ - NP;
    *(f16x4*)(Xh + (size_t)g * 4) = pack4(*(const float4*)(X + (size_t)g * 4));
  } else {
    int g = gid - NQ - NP - NX;
    if (g < kKoneTot) {
      int j = g & 7;
      int lane = (g >> 3) & 63;
      int s2 = (g >> 9) & 1;
      int nt = (g >> 10) & 7;
      int kt = g >> 13;
      int fr = lane & 15, qd = lane >> 4;
      int key = kt * 128 + nt * 16 + fr;
      int c = s2 * 32 + qd * 8 + j;
      int t2 = key / kS; int rm = key - t2 * kS;
      int h2 = rm / kWd; int w2 = rm - h2 * kWd;
      if (t2 > kT - 1) t2 = kT - 1;
      float v = 0.f;
      if (c == h2) v = 1.f;
      else if (c == 14 + w2) v = 1.f;
      else if (c == 28 + t2) v = 1.f;
      else if (c == 36 && key >= kN) v = 1.f;
      konefrag[g] = (f16)v;
    }
  }
}

// ---------------- QKV GEMM: 128x128, all-f16 operands, register prefetch --------
__global__ __launch_bounds__(256, 2) void arp_gemm_qkv(
    const f16* __restrict__ Xh, const f16* __restrict__ Wh,
    f16* __restrict__ qf, f16* __restrict__ kfrag, f16* __restrict__ vswz) {
  __shared__ char smem[34816];
  f16* sA = (f16*)smem;               // [128][40]
  f16* sB = (f16*)(smem + 10240);     // [128][40]
  f16* sE = (f16*)smem;               // [128][136] (epilogue)
  const int tid = threadIdx.x, lane = tid & 63, wv = tid >> 6;
  const int m0 = blockIdx.y * 128, n0 = blockIdx.x * 128;
  const int wm = (wv & 1) * 64, wn = (wv >> 1) * 64;
  const int frow = lane & 15, quad = lane >> 4, fcol = quad * 8;
  const f32x4 vzero = {0.f, 0.f, 0.f, 0.f};
  f32x4 acc[4][4];
#pragma unroll
  for (int i = 0; i < 4; ++i)
#pragma unroll
    for (int j = 0; j < 4; ++j) acc[i][j] = vzero;

  u32x4 pA[2], pB[2];
  const u32x4 uz = {0, 0, 0, 0};
#pragma unroll
  for (int i = 0; i < 2; ++i) {
    int idx = i * 256 + tid;
    int r = idx >> 2, c8 = (idx & 3) * 8;
    int gm = m0 + r;
    pA[i] = (gm < kM) ? *(const u32x4*)(Xh + (size_t)gm * 768 + c8) : uz;
    pB[i] = *(const u32x4*)(Wh + (size_t)(n0 + r) * 768 + c8);
  }

  for (int kt = 0; kt < 24; ++kt) {
#pragma unroll
    for (int i = 0; i < 2; ++i) {
      int idx = i * 256 + tid;
      int r = idx >> 2, c8 = (idx & 3) * 8;
      *(u32x4*)&sA[r * 40 + c8] = pA[i];
      *(u32x4*)&sB[r * 40 + c8] = pB[i];
    }
    __syncthreads();
    if (kt < 23) {
      int ko = (kt + 1) * 32;
#pragma unroll
      for (int i = 0; i < 2; ++i) {
        int idx = i * 256 + tid;
        int r = idx >> 2, c8 = (idx & 3) * 8;
        int gm = m0 + r;
        pA[i] = (gm < kM) ? *(const u32x4*)(Xh + (size_t)gm * 768 + ko + c8) : uz;
        pB[i] = *(const u32x4*)(Wh + (size_t)(n0 + r) * 768 + ko + c8);
      }
    }
    f16x8 af[4], bf[4];
#pragma unroll
    for (int t = 0; t < 4; ++t) {
      af[t] = *(const f16x8*)&sA[(wm + t * 16 + frow) * 40 + fcol];
      bf[t] = *(const f16x8*)&sB[(wn + t * 16 + frow) * 40 + fcol];
    }
#pragma unroll
    for (int mt = 0; mt < 4; ++mt)
#pragma unroll
      for (int nt = 0; nt < 4; ++nt)
        acc[mt][nt] = MFMA16(af[mt], bf[nt], acc[mt][nt]);
    __syncthreads();
  }

  const int which = n0 / 768;   // 0=q, 1=k, 2=v
  if (which == 2) {
#pragma unroll
    for (int mt = 0; mt < 4; ++mt)
#pragma unroll
      for (int nt = 0; nt < 4; ++nt) {
        int cl = wn + nt * 16 + frow;
#pragma unroll
        for (int rg = 0; rg < 4; ++rg) {
          int rl = wm + mt * 16 + quad * 4 + rg;
          sE[cl * 136 + rl] = (f16)acc[mt][nt][rg];
        }
      }
    __syncthreads();
    int cl = tid >> 1;
    int rb = (tid & 1) * 64;
    int rem = n0 + cl - 1536;
    int hh = rem >> 6, d = rem & 63;
    int td = d >> 4, fr = d & 15;
#pragma unroll
    for (int j = 0; j < 8; ++j) {
      int ms = m0 + rb + j * 8;
      if (ms < kM) {
        int bb = (ms >= kN) ? 1 : 0;
        int ns = ms - bb * kN;
        int bh = bb * kHeads + hh;
        int kt2 = ns >> 7, kr = ns & 127;
        int kc = kr >> 5, qd = (kr >> 3) & 3;
        f16* dst = vswz + ((((size_t)(bh * 13 + kt2)) * 4 + td) * 4 + kc) * 512
                        + (qd * 16 + fr) * 8;
        *(u32x4*)dst = *(const u32x4*)&sE[cl * 136 + rb + j * 8];
      }
    }
  } else {
#pragma unroll
    for (int mt = 0; mt < 4; ++mt) {
      int rbase = m0 + wm + mt * 16 + quad * 4;
#pragma unroll
      for (int nt = 0; nt < 4; ++nt) {
        int col0 = n0 + wn + nt * 16;
        int rem = col0 - which * 768;
        int hh = rem >> 6;
        int d = (rem & 63) + frow;
        int s = d >> 5, qd2 = (d >> 3) & 3, j = d & 7;
#pragma unroll
        for (int rg = 0; rg < 4; ++rg) {
          int m = rbase + rg;
          if (m < kM) {
            int bb = (m >= kN) ? 1 : 0;
            int ns = m - bb * kN;
            int bh = bb * kHeads + hh;
            float av = acc[mt][nt][rg];
            if (which == 0) {
              av *= kLog2e;
              qf[((size_t)bh * kNp + ns) * 64 + d] = (f16)av;
            } else {
              av *= 0.125f;
              int kt2 = ns >> 7, nt2 = (ns >> 4) & 7, fr = ns & 15;
              kfrag[(((size_t)(bh * 13 + kt2) * 8 + nt2) * 2 + s) * 512
                    + (qd2 * 16 + fr) * 8 + j] = (f16)av;
            }
          }
        }
      }
    }
  }
}

// ---------------- flash attention; fused qext with LDS-staged R tables ----------
// Prologue: stage Rh/Rw/Rt (69 rows) coalesced into LDS as f16 (stride 72 ->
// rows land 4 banks apart), then wave-specialized dots read LDS instead of
// gathered global. sQE + sR alias sKa/sKb (dead until barrier A).
__global__ __launch_bounds__(256, 3) void arp_attn(
    const f16* qf,
    const float* __restrict__ Rh, const float* __restrict__ Rw, const float* __restrict__ Rt,
    const f16* __restrict__ kfrag, const f16* __restrict__ konefrag,
    const f16* __restrict__ vswz, f16* qfO) {
  __shared__ char pool[49152];
  f16* sKa = (f16*)pool;             // 16384 B: K dims 0..63  [nt][s01][64][8]
  f16* sKb = (f16*)(pool + 16384);   // 16384 B: ext dims 64..127
  f16* sV  = (f16*)(pool + 32768);   // 16384 B: V frags [td][kc][64][8]
  f16* sQE = (f16*)pool;             // 8192 B:  [64][64] qe staging (prologue only)
  f16* sR  = (f16*)(pool + 8192);    // 9936 B:  69 rows x 72 f16 (prologue only)

  const int tid = threadIdx.x, lane = tid & 63, wv = tid >> 6;
  const int q0 = blockIdx.x * 64;
  const int bh = blockIdx.y;
  const int frow = lane & 15, quad = lane >> 4;
  const f32x4 vzero = {0.f, 0.f, 0.f, 0.f};

  // ---- stage R tables: rows 0..26 = Rh, 27..53 = Rw, 54..68 = Rt ----
  for (int g = tid; g < 69 * 16; g += 256) {
    int row = g >> 4, c4 = (g & 15) * 4;
    const float* src = (row < 27) ? Rh + row * 64 + c4
                     : (row < 54) ? Rw + (row - 27) * 64 + c4
                                  : Rt + (row - 54) * 64 + c4;
    *(f16x4*)&sR[row * 72 + c4] = pack4(*(const float4*)src);
  }
  __syncthreads();

  // ---- fused qext, wave-specialized, dots from LDS ----
  {
    int q = q0 + lane;
    int qc = (q < kN) ? q : kN - 1;    // clamp so table indices stay in range
    int tq = qc / kS, sr = qc - tq * kS;
    int hq = sr / kWd, wq = sr - hq * kWd;
    if (wv < 3) {
      f16x8 qh[8];
      const f16x8* qv8 = (const f16x8*)(qf + ((size_t)bh * kNp + q) * 64);
#pragma unroll
      for (int i = 0; i < 8; ++i) qh[i] = qv8[i];
      if (wv == 0) {
#pragma unroll
        for (int e = 0; e < 14; ++e)
          sQE[lane * 64 + e] = (f16)dotqLDS(qh, &sR[(hq - e + 13) * 72]);
      } else if (wv == 1) {
#pragma unroll
        for (int e = 0; e < 14; ++e)
          sQE[lane * 64 + 14 + e] = (f16)dotqLDS(qh, &sR[(wq - e + 40) * 72]);
      } else {
#pragma unroll
        for (int e = 0; e < 8; ++e)
          sQE[lane * 64 + 28 + e] = (f16)dotqLDS(qh, &sR[(tq - e + 61) * 72]);
      }
    } else {
      sQE[lane * 64 + 36] = (f16)(-30000.f);
#pragma unroll
      for (int e = 37; e < 64; ++e) sQE[lane * 64 + e] = (f16)0.f;
    }
  }
  __syncthreads();

  f16x8 aQ0, aQ1, aQE0, aQE1;
  {
    int row = q0 + wv * 16 + frow;
    const f16* qp = qf + ((size_t)bh * kNp + row) * 64;
    aQ0 = *(const f16x8*)(qp + quad * 8);
    aQ1 = *(const f16x8*)(qp + 32 + quad * 8);
    int rl = wv * 16 + frow;
    aQE0 = *(const f16x8*)&sQE[rl * 64 + quad * 8];
    aQE1 = *(const f16x8*)&sQE[rl * 64 + 32 + quad * 8];
  }
  f16x8 bOnes;
#pragma unroll
  for (int i = 0; i < 8; ++i) bOnes[i] = (frow == 0) ? (f16)1.f : (f16)0.f;

  f32x4 Oc[5];
#pragma unroll
  for (int t = 0; t < 5; ++t) Oc[t] = vzero;

  const f16* kba = kfrag + (size_t)bh * 13 * 8192;
  const f16* vba = vswz + (size_t)bh * 13 * 8192;
  f16* sPw = (f16*)(pool + wv * 4352);   // per-wave P: [16][136] f16, aliases sKa/sKb

  for (int kt = 0; kt < 13; ++kt) {
    __syncthreads();  // A: prior iter's sP/sV reads (and prologue sQE reads) done
    {
      const f16* kfa = kba + (size_t)kt * 8192;
      const f16* koa = konefrag + (size_t)kt * 8192;
      const f16* vfa = vba + (size_t)kt * 8192;
#pragma unroll
      for (int i = 0; i < 4; ++i) {
        int u = (i * 256 + tid) * 8;
        *(u32x4*)&sKa[u] = *(const u32x4*)(kfa + u);
      }
#pragma unroll
      for (int i = 0; i < 4; ++i) {
        int u = (i * 256 + tid) * 8;
        *(u32x4*)&sKb[u] = *(const u32x4*)(koa + u);
      }
#pragma unroll
      for (int i = 0; i < 4; ++i) {
        int u = (i * 256 + tid) * 8;
        *(u32x4*)&sV[u] = *(const u32x4*)(vfa + u);
      }
    }
    __syncthreads();  // B: staging visible

    f32x4 Sc[8];
#pragma unroll
    for (int nt = 0; nt < 8; ++nt) {
      const f16* ka = &sKa[nt * 1024 + lane * 8];
      const f16* kb = &sKb[nt * 1024 + lane * 8];
      f32x4 s = MFMA16(aQ0, *(const f16x8*)(ka), vzero);
      s = MFMA16(aQ1, *(const f16x8*)(ka + 512), s);
      s = MFMA16(aQE0, *(const f16x8*)(kb), s);
      Sc[nt] = MFMA16(aQE1, *(const f16x8*)(kb + 512), s);
    }
#pragma unroll
    for (int nt = 0; nt < 8; ++nt)
#pragma unroll
      for (int r = 0; r < 4; ++r)
        Sc[nt][r] = fast_exp2(Sc[nt][r]);
    f16x8 bV[4][4];
#pragma unroll
    for (int td = 0; td < 4; ++td)
#pragma unroll
      for (int kc = 0; kc < 4; ++kc)
        bV[td][kc] = *(const f16x8*)&sV[(td * 4 + kc) * 512 + lane * 8];
    __syncthreads();  // C: all QK-phase sKa/sKb reads done; safe to clobber with P

#pragma unroll
    for (int nt = 0; nt < 8; ++nt)
#pragma unroll
      for (int r = 0; r < 4; ++r)
        sPw[(quad * 4 + r) * 136 + nt * 16 + frow] = (f16)Sc[nt][r];
#pragma unroll
    for (int kc = 0; kc < 4; ++kc) {
      f16x8 aP = *(const f16x8*)&sPw[frow * 136 + kc * 32 + quad * 8];
#pragma unroll
      for (int td = 0; td < 4; ++td)
        Oc[td] = MFMA16(aP, bV[td][kc], Oc[td]);
      Oc[4] = MFMA16(aP, bOnes, Oc[4]);
    }
  }
  float lr[4];
#pragma unroll
  for (int r = 0; r < 4; ++r)
    lr[r] = 1.f / __shfl(Oc[4][r], lane & 48, 64);
#pragma unroll
  for (int td = 0; td < 4; ++td)
#pragma unroll
    for (int r = 0; r < 4; ++r) {
      int row = q0 + wv * 16 + quad * 4 + r;
      if (row < kN) {
        float val = Oc[td][r] * lr[r];
        qfO[((size_t)bh * kNp + row) * 64 + td * 16 + frow] = (f16)val;
      }
    }
}

// ---------------- proj GEMM: 64x128 tiles (grid 294 -> full occupancy) ----------
__global__ __launch_bounds__(256, 4) void arp_gemm_proj(
    const f16* A, const f16* __restrict__ Wp,
    const float* __restrict__ bias, float* __restrict__ out) {
  __shared__ f16 sA[64 * 40];     // 5120 B
  __shared__ f16 sB[128 * 40];    // 10240 B
  const int tid = threadIdx.x, lane = tid & 63, wv = tid >> 6;
  const int m0 = blockIdx.y * 64, n0 = blockIdx.x * 128;
  const int frow = lane & 15, quad = lane >> 4, fcol = quad * 8;
  const f32x4 vzero = {0.f, 0.f, 0.f, 0.f};
  f32x4 acc[8];
#pragma unroll
  for (int j = 0; j < 8; ++j) acc[j] = vzero;

  u32x4 pA, pB[2];
  {
    int r = tid >> 2, c8 = (tid & 3) * 8;
    int m = m0 + r;
    int bb = (m >= kN) ? 1 : 0;
    int ns = m - bb * kN;
    pA = *(const u32x4*)(A + ((size_t)(bb * kHeads) * kNp + ns) * 64 + c8);
#pragma unroll
    for (int i = 0; i < 2; ++i) {
      int idx = i * 256 + tid;
      int rb2 = idx >> 2, cb8 = (idx & 3) * 8;
      pB[i] = *(const u32x4*)(Wp + (size_t)(n0 + rb2) * 768 + cb8);
    }
  }

  for (int kt = 0; kt < 24; ++kt) {
    {
      int r = tid >> 2, c8 = (tid & 3) * 8;
      *(u32x4*)&sA[r * 40 + c8] = pA;
#pragma unroll
      for (int i = 0; i < 2; ++i) {
        int idx = i * 256 + tid;
        int rb2 = idx >> 2, cb8 = (idx & 3) * 8;
        *(u32x4*)&sB[rb2 * 40 + cb8] = pB[i];
      }
    }
    __syncthreads();
    if (kt < 23) {
      int k1 = kt + 1;
      int hd = k1 >> 1, dof = (k1 & 1) * 32;
      int r = tid >> 2, c8 = (tid & 3) * 8;
      int m = m0 + r;
      int bb = (m >= kN) ? 1 : 0;
      int ns = m - bb * kN;
      pA = *(const u32x4*)(A + ((size_t)(bb * kHeads + hd) * kNp + ns) * 64 + dof + c8);
#pragma unroll
      for (int i = 0; i < 2; ++i) {
        int idx = i * 256 + tid;
        int rb2 = idx >> 2, cb8 = (idx & 3) * 8;
        pB[i] = *(const u32x4*)(Wp + (size_t)(n0 + rb2) * 768 + k1 * 32 + cb8);
      }
    }
    f16x8 af = *(const f16x8*)&sA[(wv * 16 + frow) * 40 + fcol];
    f16x8 bf[8];
#pragma unroll
    for (int u = 0; u < 8; ++u)
      bf[u] = *(const f16x8*)&sB[(u * 16 + frow) * 40 + fcol];
#pragma unroll
    for (int u = 0; u < 8; ++u)
      acc[u] = MFMA16(af, bf[u], acc[u]);
    __syncthreads();
  }
#pragma unroll
  for (int u = 0; u < 8; ++u) {
    int col = n0 + u * 16 + frow;
    float bv = bias[col];
#pragma unroll
    for (int rg = 0; rg < 4; ++rg) {
      int m = m0 + wv * 16 + quad * 4 + rg;
      out[(size_t)m * 768 + col] = acc[u][rg] + bv;
    }
  }
}

extern "C" void kernel_launch(void* const* d_in, const int* in_sizes, int n_in,
                              void* d_out, int out_size, void* d_ws, size_t ws_size,
                              hipStream_t stream) {
  if (ws_size < WS_TOTAL) return;
  const float* x      = (const float*)d_in[0];
  const float* qkv_w  = (const float*)d_in[1];
  const float* proj_w = (const float*)d_in[2];
  const float* proj_b = (const float*)d_in[3];
  const float* rph    = (const float*)d_in[4];
  const float* rpw    = (const float*)d_in[5];
  const float* rpt    = (const float*)d_in[6];
  char* ws = (char*)d_ws;
  f16* Wh       = (f16*)(ws + OFF_WH);
  f16* Wp       = (f16*)(ws + OFF_WP);
  f16* qf       = (f16*)(ws + OFF_Q);     // becomes O after attn (in-place)
  f16* Xh       = (f16*)(ws + OFF_XH);
  f16* kfrag    = (f16*)(ws + OFF_KF);
  f16* konefrag = (f16*)(ws + OFF_KONE);
  f16* vswz     = (f16*)(ws + OFF_VSWZ);

  const int cvtTot = (2304 * 768 + 768 * 768 + 3136 * 768) / 4 + kKoneTot;
  arp_cvt<<<(cvtTot + 255) / 256, 256, 0, stream>>>(qkv_w, proj_w, x, Wh, Wp, Xh, konefrag);
  arp_gemm_qkv<<<dim3(18, 25), 256, 0, stream>>>(Xh, Wh, qf, kfrag, vswz);
  arp_attn<<<dim3(25, 24), 256, 0, stream>>>(qf, rph, rpw, rpt, kfrag, konefrag, vswz, qf);
  arp_gemm_proj<<<dim3(6, 49), 256, 0, stream>>>(qf, Wp, proj_b, (float*)d_out);
}